// Round 3
// baseline (4646.240 us; speedup 1.0000x reference)
//
#include <hip/hip_runtime.h>
#include <math.h>

typedef unsigned short u16;
typedef __attribute__((ext_vector_type(8))) short bf8;     // 8 x bf16 (raw bits)
typedef __attribute__((ext_vector_type(4))) float f4;

#define DEV static __device__ __forceinline__

DEV u16 f2b(float f){
  unsigned u = __builtin_bit_cast(unsigned, f);
  u += 0x7fffu + ((u >> 16) & 1u);          // round-to-nearest-even
  return (u16)(u >> 16);
}
DEV float b2f(u16 h){
  unsigned u = ((unsigned)h) << 16;
  return __builtin_bit_cast(float, u);
}

#define BATCH  8
#define NTOK   581
#define NPAD   640
#define DIM    768
#define DFF    3072
#define NHEAD  12
#define HDIM   64
#define NLAYER 12
#define MTOK   (BATCH*NTOK)     /* 4648 */
#define MPAD2  4736             /* 37*128, for 128-row tiles */
#define MCONV  (BATCH*576)      /* 4608 = 36*128 */
#define ATTN_SCALE 0.125f
#define BHEADS (BATCH*NHEAD)    /* 96 */
#define QSZ    ((long long)BHEADS*NPAD*HDIM)

enum { EPI_CONV=0, EPI_QKV, EPI_S, EPI_PV, EPI_PROJ, EPI_GELU, EPI_FC2 };

#define GLD16(g, l) __builtin_amdgcn_global_load_lds( \
    (const __attribute__((address_space(1))) unsigned*)(g), \
    (__attribute__((address_space(3))) unsigned*)(l), 16, 0, 0)

// ---------------- 128x128 tile GEMM (m97 structure) ----------------
// C = A(MxK,row) * B(NxK,row)^T. M = gridDim.y*128, N = gridDim.x*128, K%32==0.
template<int EPI>
__global__ __launch_bounds__(256) void gemm128(
    const u16* __restrict__ A, int lda,
    const u16* __restrict__ B, int ldb, int K,
    const float* __restrict__ bias,
    const float* __restrict__ aux,
    float* __restrict__ Cf,
    u16* __restrict__ Cb)
{
  const int bm = blockIdx.y * 128, bn = blockIdx.x * 128;
  __shared__ __attribute__((aligned(16))) u16 As[128*32];
  __shared__ __attribute__((aligned(16))) u16 Bs[128*32];
  const int tid  = threadIdx.x;
  const int lane = tid & 63, wid = tid >> 6;
  const int wr = wid >> 1, wc = wid & 1;            // 2x2 waves, each 64x64
  // staging: chunk c covers LDS rows [16c,16c+16); lane l -> row 16c+(l>>2), col (l&3)*8
  const int c0 = wid, c1 = wid + 4;
  const int sr0 = c0*16 + (lane >> 2), sr1 = c1*16 + (lane >> 2);
  const int sc  = (lane & 3) * 8;
  const u16* gA0 = A + (long long)(bm + sr0) * lda + sc;
  const u16* gA1 = A + (long long)(bm + sr1) * lda + sc;
  const u16* gB0 = B + (long long)(bn + sr0) * ldb + sc;
  const u16* gB1 = B + (long long)(bn + sr1) * ldb + sc;
  u16* lA0 = &As[c0*512]; u16* lA1 = &As[c1*512];   // wave-uniform LDS bases
  u16* lB0 = &Bs[c0*512]; u16* lB1 = &Bs[c1*512];
  const int frow = lane & 15, fk = (lane >> 4) * 8;
  f4 acc[4][4] = {};
  for (int k0 = 0; k0 < K; k0 += 32){
    GLD16(gA0, lA0); GLD16(gA1, lA1);
    GLD16(gB0, lB0); GLD16(gB1, lB1);
    gA0 += 32; gA1 += 32; gB0 += 32; gB1 += 32;
    __syncthreads();
    bf8 a[4], b[4];
    #pragma unroll
    for (int m = 0; m < 4; ++m) a[m] = *(const bf8*)&As[(wr*64 + m*16 + frow)*32 + fk];
    #pragma unroll
    for (int n = 0; n < 4; ++n) b[n] = *(const bf8*)&Bs[(wc*64 + n*16 + frow)*32 + fk];
    #pragma unroll
    for (int m = 0; m < 4; ++m)
    #pragma unroll
    for (int n = 0; n < 4; ++n)
      acc[m][n] = __builtin_amdgcn_mfma_f32_16x16x32_bf16(a[m], b[n], acc[m][n], 0, 0, 0);
    __syncthreads();
  }
  #pragma unroll
  for (int mi = 0; mi < 4; ++mi)
  #pragma unroll
  for (int ni = 0; ni < 4; ++ni){
    f4 v = acc[mi][ni];
    int col = bn + wc*64 + ni*16 + frow;
    int r0  = bm + wr*64 + mi*16 + (lane >> 4) * 4;
    #pragma unroll
    for (int j = 0; j < 4; ++j){
      int m = r0 + j;
      float val = v[j];
      if constexpr (EPI == EPI_CONV){
        int b = m / 576, p = m % 576;
        Cf[((long long)b*NTOK + 5 + p)*DIM + col] = val + bias[col];
      } else if constexpr (EPI == EPI_QKV){
        if (m < MTOK){
          int b = m / NTOK, t = m % NTOK;
          int which = col / DIM, rem = col % DIM;
          int h = rem / HDIM, hd = rem % HDIM;
          float x = val + bias[col];
          if (which == 0) x *= ATTN_SCALE;
          Cb[(long long)which*QSZ + (((long long)(b*NHEAD + h))*NPAD + t)*HDIM + hd] = f2b(x);
        }
      } else if constexpr (EPI == EPI_PROJ || EPI == EPI_FC2){
        if (m < MTOK)
          Cf[(long long)m*DIM + col] += aux[col] * (val + bias[col]);
      } else if constexpr (EPI == EPI_GELU){
        float x = val + bias[col];
        float g = 0.5f * x * (1.0f + erff(x * 0.70710678118f));
        Cb[(long long)m*DFF + col] = f2b(g);
      }
    }
  }
}

// ---------------- 64x64 tile GEMM (attention S / PV) ----------------
template<int EPI>
__global__ __launch_bounds__(256) void gemm_k(
    const u16* __restrict__ A, long long sAz, int lda,
    const u16* __restrict__ B, long long sBz, int ldb,
    int M, int N, int K,
    u16* __restrict__ Cb, long long sCz)
{
  const int z = blockIdx.z;
  const u16* Ab = A + (long long)z * sAz;
  const u16* Bb = B + (long long)z * sBz;
  const int bm = blockIdx.y * 64, bn = blockIdx.x * 64;
  __shared__ __attribute__((aligned(16))) u16 As[64][40];
  __shared__ __attribute__((aligned(16))) u16 Bs[64][40];
  const int tid  = threadIdx.x;
  const int lane = tid & 63, wid = tid >> 6;
  const int wr = wid >> 1, wc = wid & 1;          // 2x2 waves, each 32x32
  const int lr = tid >> 2, lc = (tid & 3) * 8;    // staging: 1 x 16B per thread
  const int frow = lane & 15, fk = (lane >> 4) * 8;
  f4 acc[2][2] = {};
  for (int k0 = 0; k0 < K; k0 += 32){
    *(bf8*)&As[lr][lc] = *(const bf8*)&Ab[(long long)(bm + lr) * lda + k0 + lc];
    *(bf8*)&Bs[lr][lc] = *(const bf8*)&Bb[(long long)(bn + lr) * ldb + k0 + lc];
    __syncthreads();
    bf8 a0 = *(const bf8*)&As[wr*32 +      frow][fk];
    bf8 a1 = *(const bf8*)&As[wr*32 + 16 + frow][fk];
    bf8 b0 = *(const bf8*)&Bs[wc*32 +      frow][fk];
    bf8 b1 = *(const bf8*)&Bs[wc*32 + 16 + frow][fk];
    acc[0][0] = __builtin_amdgcn_mfma_f32_16x16x32_bf16(a0, b0, acc[0][0], 0, 0, 0);
    acc[0][1] = __builtin_amdgcn_mfma_f32_16x16x32_bf16(a0, b1, acc[0][1], 0, 0, 0);
    acc[1][0] = __builtin_amdgcn_mfma_f32_16x16x32_bf16(a1, b0, acc[1][0], 0, 0, 0);
    acc[1][1] = __builtin_amdgcn_mfma_f32_16x16x32_bf16(a1, b1, acc[1][1], 0, 0, 0);
    __syncthreads();
  }
  #pragma unroll
  for (int mi = 0; mi < 2; ++mi)
  #pragma unroll
  for (int ni = 0; ni < 2; ++ni){
    f4 v = acc[mi][ni];
    int col = bn + wc*32 + ni*16 + frow;
    int r0  = bm + wr*32 + mi*16 + (lane >> 4) * 4;
    #pragma unroll
    for (int j = 0; j < 4; ++j){
      int m = r0 + j;
      float val = v[j];
      if constexpr (EPI == EPI_S){
        Cb[(long long)z*sCz + (long long)m*NPAD + col] = f2b(val);
      } else if constexpr (EPI == EPI_PV){
        if (m < NTOK)
          Cb[(((long long)(z / NHEAD))*NTOK + m)*DIM + (z % NHEAD)*HDIM + col] = f2b(val);
      }
    }
  }
}

// LayerNorm over D=768 per row; writes bf16 (F32OUT=0) or f32 (F32OUT=1).
template<int F32OUT>
__global__ __launch_bounds__(256) void ln_k(const float* __restrict__ x,
    const float* __restrict__ s, const float* __restrict__ b,
    u16* __restrict__ ob, float* __restrict__ of)
{
  const long long row = blockIdx.x;
  const float* xr = x + row * DIM;
  const int t = threadIdx.x;
  float v0 = xr[t], v1 = xr[t + 256], v2 = xr[t + 512];
  float sum = v0 + v1 + v2;
  #pragma unroll
  for (int o = 32; o; o >>= 1) sum += __shfl_down(sum, o);
  __shared__ float r1[4], r2[4];
  const int lane = t & 63, w = t >> 6;
  if (lane == 0) r1[w] = sum;
  __syncthreads();
  float mu = (r1[0] + r1[1] + r1[2] + r1[3]) * (1.0f / DIM);
  float d0 = v0 - mu, d1 = v1 - mu, d2 = v2 - mu;
  float vs = d0*d0 + d1*d1 + d2*d2;
  #pragma unroll
  for (int o = 32; o; o >>= 1) vs += __shfl_down(vs, o);
  if (lane == 0) r2[w] = vs;
  __syncthreads();
  float inv = 1.0f / sqrtf((r2[0] + r2[1] + r2[2] + r2[3]) * (1.0f / DIM) + 1e-6f);
  if constexpr (F32OUT){
    float* orow = of + row * DIM;
    orow[t]       = d0 * inv * s[t]       + b[t];
    orow[t + 256] = d1 * inv * s[t + 256] + b[t + 256];
    orow[t + 512] = d2 * inv * s[t + 512] + b[t + 512];
  } else {
    u16* orow = ob + row * DIM;
    orow[t]       = f2b(d0 * inv * s[t]       + b[t]);
    orow[t + 256] = f2b(d1 * inv * s[t + 256] + b[t + 256]);
    orow[t + 512] = f2b(d2 * inv * s[t + 512] + b[t + 512]);
  }
}

// Row softmax over cols [0,581); zeroes pad cols [581,640). In-place on bf16 S.
__global__ __launch_bounds__(256) void softmax_k(u16* __restrict__ S)
{
  const long long base = ((long long)blockIdx.y * NPAD + blockIdx.x) * NPAD;
  const int t = threadIdx.x;
  float v0 = b2f(S[base + t]);
  float v1 = b2f(S[base + t + 256]);
  const bool has2 = (t + 512) < NTOK;
  float v2 = has2 ? b2f(S[base + t + 512]) : -1e30f;
  float mx = fmaxf(fmaxf(v0, v1), v2);
  #pragma unroll
  for (int o = 32; o; o >>= 1) mx = fmaxf(mx, __shfl_down(mx, o));
  __shared__ float r1[4], r2[4];
  const int lane = t & 63, w = t >> 6;
  if (lane == 0) r1[w] = mx;
  __syncthreads();
  mx = fmaxf(fmaxf(r1[0], r1[1]), fmaxf(r1[2], r1[3]));
  float e0 = expf(v0 - mx), e1 = expf(v1 - mx), e2 = has2 ? expf(v2 - mx) : 0.0f;
  float sm = e0 + e1 + e2;
  #pragma unroll
  for (int o = 32; o; o >>= 1) sm += __shfl_down(sm, o);
  if (lane == 0) r2[w] = sm;
  __syncthreads();
  float inv = 1.0f / (r2[0] + r2[1] + r2[2] + r2[3]);
  S[base + t]       = f2b(e0 * inv);
  S[base + t + 256] = f2b(e1 * inv);
  if (t + 512 < NPAD) S[base + t + 512] = f2b(has2 ? e2 * inv : 0.0f);
}

__global__ void ropetab_k(const float* __restrict__ periods, float* __restrict__ tab)
{
  int idx = blockIdx.x * blockDim.x + threadIdx.x;
  if (idx >= 24 * 16) return;
  int c = idx >> 4, f = idx & 15;
  float fr = 6.283185307179586f / periods[f];
  float a = (float)c * fr;
  tab[idx]       = cosf(a);
  tab[384 + idx] = sinf(a);
}

__global__ __launch_bounds__(256) void rope_k(u16* __restrict__ Q, u16* __restrict__ K,
                                              const float* __restrict__ tab)
{
  int idx = blockIdx.x * blockDim.x + threadIdx.x;
  if (idx >= BHEADS * 576 * 32) return;
  int f  = idx & 31;
  int p  = (idx >> 5) % 576;
  int bh = idx / (576 * 32);
  int px = p % 24, py = p / 24;
  float c, s; int d0;
  if (f < 16){ c = tab[px*16 + f];        s = tab[384 + px*16 + f];        d0 = 2*f; }
  else       { int ff = f - 16;
               c = tab[py*16 + ff];       s = tab[384 + py*16 + ff];       d0 = 32 + 2*ff; }
  long long off = (((long long)bh) * NPAD + 5 + p) * HDIM + d0;
  float qe = b2f(Q[off]), qo = b2f(Q[off + 1]);
  Q[off]     = f2b(qe * c - qo * s);
  Q[off + 1] = f2b(qe * s + qo * c);
  float ke = b2f(K[off]), ko = b2f(K[off + 1]);
  K[off]     = f2b(ke * c - ko * s);
  K[off + 1] = f2b(ke * s + ko * c);
}

__global__ void initx_k(float* __restrict__ x, const float* __restrict__ cls,
                        const float* __restrict__ stor)
{
  int idx = blockIdx.x * blockDim.x + threadIdx.x;
  if (idx >= BATCH * 5 * DIM) return;
  int d = idx % DIM; int t = (idx / DIM) % 5; int b = idx / (5 * DIM);
  x[((long long)b * NTOK + t) * DIM + d] = (t == 0) ? cls[d] : stor[(t - 1) * DIM + d];
}

__global__ void patch_k(const float* __restrict__ px, u16* __restrict__ Ap)
{
  int idx = blockIdx.x * blockDim.x + threadIdx.x;
  if (idx >= MCONV * DIM) return;
  int k = idx % DIM, m = idx / DIM;
  int b = m / 576, r = m % 576, hp = r / 24, wp = r % 24;
  int c = k / 256, rem = k % 256, p = rem / 16, q = rem % 16;
  float v = px[((((long long)b * 3 + c) * 384) + hp * 16 + p) * 384 + wp * 16 + q];
  Ap[idx] = f2b(v);
}

__global__ void vt_k(const u16* __restrict__ V, u16* __restrict__ VT)
{
  int idx = blockIdx.x * blockDim.x + threadIdx.x;
  if (idx >= BHEADS * NPAD * HDIM) return;
  int hd = idx % HDIM; int t = (idx / HDIM) % NPAD; int bh = idx / (NPAD * HDIM);
  VT[(((long long)bh) * HDIM + hd) * NPAD + t] = V[idx];
}

__global__ void cvt_k(const float* __restrict__ src, u16* __restrict__ dst, long long n)
{
  long long i = (long long)blockIdx.x * blockDim.x + threadIdx.x;
  long long stride = (long long)gridDim.x * blockDim.x;
  for (; i < n; i += stride) dst[i] = f2b(src[i]);
}

__global__ void biaseff_k(const float* __restrict__ qb, const float* __restrict__ bm,
                          float* __restrict__ out, int n)
{
  int i = blockIdx.x * blockDim.x + threadIdx.x;
  if (i < n) out[i] = qb[i] * bm[i];
}

extern "C" void kernel_launch(void* const* d_in, const int* in_sizes, int n_in,
                              void* d_out, int out_size, void* d_ws, size_t ws_size,
                              hipStream_t stream)
{
  const float* pixel   = (const float*)d_in[0];
  const float* conv_w  = (const float*)d_in[1];
  const float* conv_b  = (const float*)d_in[2];
  const float* cls     = (const float*)d_in[3];
  const float* stor    = (const float*)d_in[4];
  const float* periods = (const float*)d_in[5];
  const float* ln1s    = (const float*)d_in[6];
  const float* ln1b    = (const float*)d_in[7];
  const float* qkvw    = (const float*)d_in[8];
  const float* qkvb    = (const float*)d_in[9];
  const float* bmask   = (const float*)d_in[10];
  const float* projw   = (const float*)d_in[11];
  const float* projb   = (const float*)d_in[12];
  const float* ls1     = (const float*)d_in[13];
  const float* ln2s    = (const float*)d_in[14];
  const float* ln2b    = (const float*)d_in[15];
  const float* fc1w    = (const float*)d_in[16];
  const float* fc1b    = (const float*)d_in[17];
  const float* fc2w    = (const float*)d_in[18];
  const float* fc2b    = (const float*)d_in[19];
  const float* ls2     = (const float*)d_in[20];
  const float* lnfs    = (const float*)d_in[21];
  const float* lnfb    = (const float*)d_in[22];

  char* wsp = (char*)d_ws;
  auto alloc = [&](long long bytes) -> char* {
    char* p = wsp; wsp += (bytes + 255) & ~255LL; return p;
  };
  u16*   wqkv  = (u16*)  alloc((long long)NLAYER*2304*768*2);
  u16*   wproj = (u16*)  alloc((long long)NLAYER*768*768*2);
  u16*   wfc1  = (u16*)  alloc((long long)NLAYER*3072*768*2);
  u16*   wfc2  = (u16*)  alloc((long long)NLAYER*768*3072*2);
  u16*   wconv = (u16*)  alloc((long long)768*768*2);
  float* beff  = (float*)alloc((long long)NLAYER*2304*4);
  float* x     = (float*)alloc((long long)MPAD2*DIM*4);
  u16*   h     = (u16*)  alloc((long long)MPAD2*DIM*2);
  u16*   obuf  = (u16*)  alloc((long long)MPAD2*DIM*2);
  u16*   mlp   = (u16*)  alloc((long long)MPAD2*DFF*2);
  u16*   Ap    = (u16*)  alloc((long long)MCONV*DIM*2);
  u16*   Q     = (u16*)  alloc(QSZ*2*3);
  u16*   Kb    = Q + QSZ;
  u16*   Vb    = Q + 2*QSZ;
  u16*   VT    = (u16*)  alloc(QSZ*2);
  u16*   S     = (u16*)  alloc((long long)BHEADS*NPAD*NPAD*2);
  float* tab   = (float*)alloc((long long)2*24*16*4);
  if ((size_t)(wsp - (char*)d_ws) > ws_size) return;  // workspace too small

  auto cvt = [&](const float* src, u16* dst, long long n){
    long long nb = (n + 255) / 256; if (nb > 4096) nb = 4096;
    cvt_k<<<(int)nb, 256, 0, stream>>>(src, dst, n);
  };
  cvt(qkvw,  wqkv,  (long long)NLAYER*2304*768);
  cvt(projw, wproj, (long long)NLAYER*768*768);
  cvt(fc1w,  wfc1,  (long long)NLAYER*3072*768);
  cvt(fc2w,  wfc2,  (long long)NLAYER*768*3072);
  cvt(conv_w, wconv, (long long)768*768);
  biaseff_k<<<(NLAYER*2304 + 255)/256, 256, 0, stream>>>(qkvb, bmask, beff, NLAYER*2304);
  ropetab_k<<<2, 256, 0, stream>>>(periods, tab);
  hipMemsetAsync(Q, 0, (size_t)QSZ*2*3, stream);   // Q/K/V pad rows must be zero

  patch_k<<<(MCONV*DIM + 255)/256, 256, 0, stream>>>(pixel, Ap);
  initx_k<<<(BATCH*5*DIM + 255)/256, 256, 0, stream>>>(x, cls, stor);
  gemm128<EPI_CONV><<<dim3(DIM/128, MCONV/128), 256, 0, stream>>>(
      Ap, DIM, wconv, DIM, DIM, conv_b, nullptr, x, nullptr);

  for (int l = 0; l < NLAYER; ++l){
    ln_k<0><<<MTOK, 256, 0, stream>>>(x, ln1s + l*DIM, ln1b + l*DIM, h, nullptr);
    gemm128<EPI_QKV><<<dim3(2304/128, MPAD2/128), 256, 0, stream>>>(
        h, DIM, wqkv + (long long)l*2304*768, DIM, DIM,
        beff + l*2304, nullptr, nullptr, Q);
    rope_k<<<(BHEADS*576*32 + 255)/256, 256, 0, stream>>>(Q, Kb, tab);
    gemm_k<EPI_S><<<dim3(NPAD/64, NPAD/64, BHEADS), 256, 0, stream>>>(
        Q, (long long)NPAD*HDIM, HDIM, Kb, (long long)NPAD*HDIM, HDIM,
        NPAD, NPAD, HDIM, S, (long long)NPAD*NPAD);
    softmax_k<<<dim3(NTOK, BHEADS), 256, 0, stream>>>(S);
    vt_k<<<(BHEADS*NPAD*HDIM + 255)/256, 256, 0, stream>>>(Vb, VT);
    gemm_k<EPI_PV><<<dim3(1, NPAD/64, BHEADS), 256, 0, stream>>>(
        S, (long long)NPAD*NPAD, NPAD, VT, (long long)HDIM*NPAD, NPAD,
        NPAD, HDIM, NPAD, obuf, 0);
    gemm128<EPI_PROJ><<<dim3(DIM/128, MPAD2/128), 256, 0, stream>>>(
        obuf, DIM, wproj + (long long)l*768*768, DIM, DIM,
        projb + l*DIM, ls1 + l*DIM, x, nullptr);
    ln_k<0><<<MTOK, 256, 0, stream>>>(x, ln2s + l*DIM, ln2b + l*DIM, h, nullptr);
    gemm128<EPI_GELU><<<dim3(DFF/128, MPAD2/128), 256, 0, stream>>>(
        h, DIM, wfc1 + (long long)l*3072*768, DIM, DIM,
        fc1b + l*DFF, nullptr, nullptr, mlp);
    gemm128<EPI_FC2><<<dim3(DIM/128, MPAD2/128), 256, 0, stream>>>(
        mlp, DFF, wfc2 + (long long)l*768*3072, DFF, DFF,
        fc2b + l*DIM, ls2 + l*DIM, x, nullptr);
  }
  ln_k<1><<<MTOK, 256, 0, stream>>>(x, lnfs, lnfb, nullptr, (float*)d_out);
}

// Round 4
// 4075.996 us; speedup vs baseline: 1.1399x; 1.1399x over previous
//
#include <hip/hip_runtime.h>
#include <math.h>

typedef unsigned short u16;
typedef __attribute__((ext_vector_type(8))) short bf8;     // 8 x bf16 (raw bits)
typedef __attribute__((ext_vector_type(4))) float f4;

#define DEV static __device__ __forceinline__

DEV u16 f2b(float f){
  unsigned u = __builtin_bit_cast(unsigned, f);
  u += 0x7fffu + ((u >> 16) & 1u);          // round-to-nearest-even
  return (u16)(u >> 16);
}
DEV float b2f(u16 h){
  unsigned u = ((unsigned)h) << 16;
  return __builtin_bit_cast(float, u);
}

#define BATCH  8
#define NTOK   581
#define NPAD   640
#define DIM    768
#define DFF    3072
#define NHEAD  12
#define HDIM   64
#define NLAYER 12
#define MTOK   (BATCH*NTOK)     /* 4648 */
#define MPAD2  4736             /* 37*128, for 128-row tiles */
#define MCONV  (BATCH*576)      /* 4608 = 36*128 */
#define ATTN_SCALE 0.125f
#define BHEADS (BATCH*NHEAD)    /* 96 */
#define QSZ    ((long long)BHEADS*NPAD*HDIM)

enum { EPI_CONV=0, EPI_QKV, EPI_S, EPI_PV, EPI_PROJ, EPI_GELU, EPI_FC2 };

#define GLD16(g, l) __builtin_amdgcn_global_load_lds( \
    (const __attribute__((address_space(1))) unsigned*)(g), \
    (__attribute__((address_space(3))) unsigned*)(l), 16, 0, 0)

// ---------------- 128xBN tile GEMM, 2-phase double-buffered ----------------
// C = A(MxK,row) * B(NxK,row)^T. M = gridDim.y*128, N = gridDim.x*BN, K%32==0.
template<int EPI, int BN>
__global__ __launch_bounds__(256) void gemm128(
    const u16* __restrict__ A, int lda,
    const u16* __restrict__ B, int ldb, int K,
    const float* __restrict__ bias,
    const float* __restrict__ aux,
    float* __restrict__ Cf,
    u16* __restrict__ Cb)
{
  constexpr int NN = BN / 32;                       // B-frags per wave (2 or 4)
  const int bm = blockIdx.y * 128, bn = blockIdx.x * BN;
  __shared__ __attribute__((aligned(16))) u16 As[2][128*32];
  __shared__ __attribute__((aligned(16))) u16 Bs[2][BN*32];
  const int tid  = threadIdx.x;
  const int lane = tid & 63, wid = tid >> 6;
  const int wr = wid >> 1, wc = wid & 1;            // 2x2 waves; wave tile 64 x BN/2
  // staging chunk c covers LDS rows [16c,16c+16): lane l -> row 16c+(l>>2), col (l&3)*8
  const int c0 = wid, c1 = wid + 4;
  const int sr0 = c0*16 + (lane >> 2), sr1 = c1*16 + (lane >> 2);
  const int sc  = (lane & 3) * 8;
  const u16* gA0 = A + (long long)(bm + sr0) * lda + sc;
  const u16* gA1 = A + (long long)(bm + sr1) * lda + sc;
  const u16* gB0 = B + (long long)(bn + sr0) * ldb + sc;
  const u16* gB1 = B + (long long)(bn + sr1) * ldb + sc;   // used only if BN==128
  auto stage = [&](int buf){
    GLD16(gA0, &As[buf][c0*512]);
    GLD16(gA1, &As[buf][c1*512]);
    GLD16(gB0, &Bs[buf][c0*512]);
    if constexpr (BN == 128) GLD16(gB1, &Bs[buf][c1*512]);
    gA0 += 32; gA1 += 32; gB0 += 32;
    if constexpr (BN == 128) gB1 += 32;
  };
  const int frow = lane & 15, fk = (lane >> 4) * 8;
  f4 acc[4][NN] = {};
  const int NIT = K >> 5;
  int cur = 0;
  stage(0);
  __syncthreads();
  for (int it = 0; it < NIT; ++it){
    if (it + 1 < NIT) stage(cur ^ 1);               // prefetch next tile (async)
    bf8 a[4], b[NN];
    #pragma unroll
    for (int m = 0; m < 4; ++m) a[m] = *(const bf8*)&As[cur][(wr*64 + m*16 + frow)*32 + fk];
    #pragma unroll
    for (int n = 0; n < NN; ++n) b[n] = *(const bf8*)&Bs[cur][(wc*(BN/2) + n*16 + frow)*32 + fk];
    #pragma unroll
    for (int m = 0; m < 4; ++m)
    #pragma unroll
    for (int n = 0; n < NN; ++n)
      acc[m][n] = __builtin_amdgcn_mfma_f32_16x16x32_bf16(a[m], b[n], acc[m][n], 0, 0, 0);
    __syncthreads();                                // drains prefetch; frees cur for reuse
    cur ^= 1;
  }
  #pragma unroll
  for (int mi = 0; mi < 4; ++mi)
  #pragma unroll
  for (int ni = 0; ni < NN; ++ni){
    f4 v = acc[mi][ni];
    int col = bn + wc*(BN/2) + ni*16 + frow;
    int r0  = bm + wr*64 + mi*16 + (lane >> 4) * 4;
    #pragma unroll
    for (int j = 0; j < 4; ++j){
      int m = r0 + j;
      float val = v[j];
      if constexpr (EPI == EPI_CONV){
        int b = m / 576, p = m % 576;
        Cf[((long long)b*NTOK + 5 + p)*DIM + col] = val + bias[col];
      } else if constexpr (EPI == EPI_QKV){
        if (m < MTOK){
          int b = m / NTOK, t = m % NTOK;
          int which = col / DIM, rem = col % DIM;
          int h = rem / HDIM, hd = rem % HDIM;
          float x = val + bias[col];
          if (which == 0) x *= ATTN_SCALE;
          Cb[(long long)which*QSZ + (((long long)(b*NHEAD + h))*NPAD + t)*HDIM + hd] = f2b(x);
        }
      } else if constexpr (EPI == EPI_PROJ || EPI == EPI_FC2){
        if (m < MTOK)
          Cf[(long long)m*DIM + col] += aux[col] * (val + bias[col]);
      } else if constexpr (EPI == EPI_GELU){
        float x = val + bias[col];
        float g = 0.5f * x * (1.0f + erff(x * 0.70710678118f));
        Cb[(long long)m*DFF + col] = f2b(g);
      }
    }
  }
}

// ---------------- 64x64 tile GEMM (attention S / PV) ----------------
template<int EPI>
__global__ __launch_bounds__(256) void gemm_k(
    const u16* __restrict__ A, long long sAz, int lda,
    const u16* __restrict__ B, long long sBz, int ldb,
    int M, int N, int K,
    u16* __restrict__ Cb, long long sCz)
{
  const int z = blockIdx.z;
  const u16* Ab = A + (long long)z * sAz;
  const u16* Bb = B + (long long)z * sBz;
  const int bm = blockIdx.y * 64, bn = blockIdx.x * 64;
  __shared__ __attribute__((aligned(16))) u16 As[64][40];
  __shared__ __attribute__((aligned(16))) u16 Bs[64][40];
  const int tid  = threadIdx.x;
  const int lane = tid & 63, wid = tid >> 6;
  const int wr = wid >> 1, wc = wid & 1;          // 2x2 waves, each 32x32
  const int lr = tid >> 2, lc = (tid & 3) * 8;    // staging: 1 x 16B per thread
  const int frow = lane & 15, fk = (lane >> 4) * 8;
  f4 acc[2][2] = {};
  for (int k0 = 0; k0 < K; k0 += 32){
    *(bf8*)&As[lr][lc] = *(const bf8*)&Ab[(long long)(bm + lr) * lda + k0 + lc];
    *(bf8*)&Bs[lr][lc] = *(const bf8*)&Bb[(long long)(bn + lr) * ldb + k0 + lc];
    __syncthreads();
    bf8 a0 = *(const bf8*)&As[wr*32 +      frow][fk];
    bf8 a1 = *(const bf8*)&As[wr*32 + 16 + frow][fk];
    bf8 b0 = *(const bf8*)&Bs[wc*32 +      frow][fk];
    bf8 b1 = *(const bf8*)&Bs[wc*32 + 16 + frow][fk];
    acc[0][0] = __builtin_amdgcn_mfma_f32_16x16x32_bf16(a0, b0, acc[0][0], 0, 0, 0);
    acc[0][1] = __builtin_amdgcn_mfma_f32_16x16x32_bf16(a0, b1, acc[0][1], 0, 0, 0);
    acc[1][0] = __builtin_amdgcn_mfma_f32_16x16x32_bf16(a1, b0, acc[1][0], 0, 0, 0);
    acc[1][1] = __builtin_amdgcn_mfma_f32_16x16x32_bf16(a1, b1, acc[1][1], 0, 0, 0);
    __syncthreads();
  }
  #pragma unroll
  for (int mi = 0; mi < 2; ++mi)
  #pragma unroll
  for (int ni = 0; ni < 2; ++ni){
    f4 v = acc[mi][ni];
    int col = bn + wc*32 + ni*16 + frow;
    int r0  = bm + wr*32 + mi*16 + (lane >> 4) * 4;
    #pragma unroll
    for (int j = 0; j < 4; ++j){
      int m = r0 + j;
      float val = v[j];
      if constexpr (EPI == EPI_S){
        Cb[(long long)z*sCz + (long long)m*NPAD + col] = f2b(val);
      } else if constexpr (EPI == EPI_PV){
        if (m < NTOK)
          Cb[(((long long)(z / NHEAD))*NTOK + m)*DIM + (z % NHEAD)*HDIM + col] = f2b(val);
      }
    }
  }
}

// LayerNorm over D=768 per row; writes bf16 (F32OUT=0) or f32 (F32OUT=1).
template<int F32OUT>
__global__ __launch_bounds__(256) void ln_k(const float* __restrict__ x,
    const float* __restrict__ s, const float* __restrict__ b,
    u16* __restrict__ ob, float* __restrict__ of)
{
  const long long row = blockIdx.x;
  const float* xr = x + row * DIM;
  const int t = threadIdx.x;
  float v0 = xr[t], v1 = xr[t + 256], v2 = xr[t + 512];
  float sum = v0 + v1 + v2;
  #pragma unroll
  for (int o = 32; o; o >>= 1) sum += __shfl_down(sum, o);
  __shared__ float r1[4], r2[4];
  const int lane = t & 63, w = t >> 6;
  if (lane == 0) r1[w] = sum;
  __syncthreads();
  float mu = (r1[0] + r1[1] + r1[2] + r1[3]) * (1.0f / DIM);
  float d0 = v0 - mu, d1 = v1 - mu, d2 = v2 - mu;
  float vs = d0*d0 + d1*d1 + d2*d2;
  #pragma unroll
  for (int o = 32; o; o >>= 1) vs += __shfl_down(vs, o);
  if (lane == 0) r2[w] = vs;
  __syncthreads();
  float inv = 1.0f / sqrtf((r2[0] + r2[1] + r2[2] + r2[3]) * (1.0f / DIM) + 1e-6f);
  if constexpr (F32OUT){
    float* orow = of + row * DIM;
    orow[t]       = d0 * inv * s[t]       + b[t];
    orow[t + 256] = d1 * inv * s[t + 256] + b[t + 256];
    orow[t + 512] = d2 * inv * s[t + 512] + b[t + 512];
  } else {
    u16* orow = ob + row * DIM;
    orow[t]       = f2b(d0 * inv * s[t]       + b[t]);
    orow[t + 256] = f2b(d1 * inv * s[t + 256] + b[t + 256]);
    orow[t + 512] = f2b(d2 * inv * s[t + 512] + b[t + 512]);
  }
}

// Row softmax over cols [0,581); zeroes pad cols [581,640). In-place on bf16 S.
__global__ __launch_bounds__(256) void softmax_k(u16* __restrict__ S)
{
  const long long base = ((long long)blockIdx.y * NPAD + blockIdx.x) * NPAD;
  const int t = threadIdx.x;
  float v0 = b2f(S[base + t]);
  float v1 = b2f(S[base + t + 256]);
  const bool has2 = (t + 512) < NTOK;
  float v2 = has2 ? b2f(S[base + t + 512]) : -1e30f;
  float mx = fmaxf(fmaxf(v0, v1), v2);
  #pragma unroll
  for (int o = 32; o; o >>= 1) mx = fmaxf(mx, __shfl_down(mx, o));
  __shared__ float r1[4], r2[4];
  const int lane = t & 63, w = t >> 6;
  if (lane == 0) r1[w] = mx;
  __syncthreads();
  mx = fmaxf(fmaxf(r1[0], r1[1]), fmaxf(r1[2], r1[3]));
  float e0 = expf(v0 - mx), e1 = expf(v1 - mx), e2 = has2 ? expf(v2 - mx) : 0.0f;
  float sm = e0 + e1 + e2;
  #pragma unroll
  for (int o = 32; o; o >>= 1) sm += __shfl_down(sm, o);
  if (lane == 0) r2[w] = sm;
  __syncthreads();
  float inv = 1.0f / (r2[0] + r2[1] + r2[2] + r2[3]);
  S[base + t]       = f2b(e0 * inv);
  S[base + t + 256] = f2b(e1 * inv);
  if (t + 512 < NPAD) S[base + t + 512] = f2b(has2 ? e2 * inv : 0.0f);
}

__global__ void ropetab_k(const float* __restrict__ periods, float* __restrict__ tab)
{
  int idx = blockIdx.x * blockDim.x + threadIdx.x;
  if (idx >= 24 * 16) return;
  int c = idx >> 4, f = idx & 15;
  float fr = 6.283185307179586f / periods[f];
  float a = (float)c * fr;
  tab[idx]       = cosf(a);
  tab[384 + idx] = sinf(a);
}

__global__ __launch_bounds__(256) void rope_k(u16* __restrict__ Q, u16* __restrict__ K,
                                              const float* __restrict__ tab)
{
  int idx = blockIdx.x * blockDim.x + threadIdx.x;
  if (idx >= BHEADS * 576 * 32) return;
  int f  = idx & 31;
  int p  = (idx >> 5) % 576;
  int bh = idx / (576 * 32);
  int px = p % 24, py = p / 24;
  float c, s; int d0;
  if (f < 16){ c = tab[px*16 + f];        s = tab[384 + px*16 + f];        d0 = 2*f; }
  else       { int ff = f - 16;
               c = tab[py*16 + ff];       s = tab[384 + py*16 + ff];       d0 = 32 + 2*ff; }
  long long off = (((long long)bh) * NPAD + 5 + p) * HDIM + d0;
  float qe = b2f(Q[off]), qo = b2f(Q[off + 1]);
  Q[off]     = f2b(qe * c - qo * s);
  Q[off + 1] = f2b(qe * s + qo * c);
  float ke = b2f(K[off]), ko = b2f(K[off + 1]);
  K[off]     = f2b(ke * c - ko * s);
  K[off + 1] = f2b(ke * s + ko * c);
}

__global__ void initx_k(float* __restrict__ x, const float* __restrict__ cls,
                        const float* __restrict__ stor)
{
  int idx = blockIdx.x * blockDim.x + threadIdx.x;
  if (idx >= BATCH * 5 * DIM) return;
  int d = idx % DIM; int t = (idx / DIM) % 5; int b = idx / (5 * DIM);
  x[((long long)b * NTOK + t) * DIM + d] = (t == 0) ? cls[d] : stor[(t - 1) * DIM + d];
}

__global__ void patch_k(const float* __restrict__ px, u16* __restrict__ Ap)
{
  int idx = blockIdx.x * blockDim.x + threadIdx.x;
  if (idx >= MCONV * DIM) return;
  int k = idx % DIM, m = idx / DIM;
  int b = m / 576, r = m % 576, hp = r / 24, wp = r % 24;
  int c = k / 256, rem = k % 256, p = rem / 16, q = rem % 16;
  float v = px[((((long long)b * 3 + c) * 384) + hp * 16 + p) * 384 + wp * 16 + q];
  Ap[idx] = f2b(v);
}

__global__ void vt_k(const u16* __restrict__ V, u16* __restrict__ VT)
{
  int idx = blockIdx.x * blockDim.x + threadIdx.x;
  if (idx >= BHEADS * NPAD * HDIM) return;
  int hd = idx % HDIM; int t = (idx / HDIM) % NPAD; int bh = idx / (NPAD * HDIM);
  VT[(((long long)bh) * HDIM + hd) * NPAD + t] = V[idx];
}

__global__ void cvt_k(const float* __restrict__ src, u16* __restrict__ dst, long long n)
{
  long long i = (long long)blockIdx.x * blockDim.x + threadIdx.x;
  long long stride = (long long)gridDim.x * blockDim.x;
  for (; i < n; i += stride) dst[i] = f2b(src[i]);
}

__global__ void biaseff_k(const float* __restrict__ qb, const float* __restrict__ bm,
                          float* __restrict__ out, int n)
{
  int i = blockIdx.x * blockDim.x + threadIdx.x;
  if (i < n) out[i] = qb[i] * bm[i];
}

extern "C" void kernel_launch(void* const* d_in, const int* in_sizes, int n_in,
                              void* d_out, int out_size, void* d_ws, size_t ws_size,
                              hipStream_t stream)
{
  const float* pixel   = (const float*)d_in[0];
  const float* conv_w  = (const float*)d_in[1];
  const float* conv_b  = (const float*)d_in[2];
  const float* cls     = (const float*)d_in[3];
  const float* stor    = (const float*)d_in[4];
  const float* periods = (const float*)d_in[5];
  const float* ln1s    = (const float*)d_in[6];
  const float* ln1b    = (const float*)d_in[7];
  const float* qkvw    = (const float*)d_in[8];
  const float* qkvb    = (const float*)d_in[9];
  const float* bmask   = (const float*)d_in[10];
  const float* projw   = (const float*)d_in[11];
  const float* projb   = (const float*)d_in[12];
  const float* ls1     = (const float*)d_in[13];
  const float* ln2s    = (const float*)d_in[14];
  const float* ln2b    = (const float*)d_in[15];
  const float* fc1w    = (const float*)d_in[16];
  const float* fc1b    = (const float*)d_in[17];
  const float* fc2w    = (const float*)d_in[18];
  const float* fc2b    = (const float*)d_in[19];
  const float* ls2     = (const float*)d_in[20];
  const float* lnfs    = (const float*)d_in[21];
  const float* lnfb    = (const float*)d_in[22];

  char* wsp = (char*)d_ws;
  auto alloc = [&](long long bytes) -> char* {
    char* p = wsp; wsp += (bytes + 255) & ~255LL; return p;
  };
  u16*   wqkv  = (u16*)  alloc((long long)NLAYER*2304*768*2);
  u16*   wproj = (u16*)  alloc((long long)NLAYER*768*768*2);
  u16*   wfc1  = (u16*)  alloc((long long)NLAYER*3072*768*2);
  u16*   wfc2  = (u16*)  alloc((long long)NLAYER*768*3072*2);
  u16*   wconv = (u16*)  alloc((long long)768*768*2);
  float* beff  = (float*)alloc((long long)NLAYER*2304*4);
  float* x     = (float*)alloc((long long)MPAD2*DIM*4);
  u16*   h     = (u16*)  alloc((long long)MPAD2*DIM*2);
  u16*   obuf  = (u16*)  alloc((long long)MPAD2*DIM*2);
  u16*   mlp   = (u16*)  alloc((long long)MPAD2*DFF*2);
  u16*   Ap    = (u16*)  alloc((long long)MCONV*DIM*2);
  u16*   Q     = (u16*)  alloc(QSZ*2*3);
  u16*   Kb    = Q + QSZ;
  u16*   Vb    = Q + 2*QSZ;
  u16*   VT    = (u16*)  alloc(QSZ*2);
  u16*   S     = (u16*)  alloc((long long)BHEADS*NPAD*NPAD*2);
  float* tab   = (float*)alloc((long long)2*24*16*4);
  if ((size_t)(wsp - (char*)d_ws) > ws_size) return;  // workspace too small

  auto cvt = [&](const float* src, u16* dst, long long n){
    long long nb = (n + 255) / 256; if (nb > 4096) nb = 4096;
    cvt_k<<<(int)nb, 256, 0, stream>>>(src, dst, n);
  };
  cvt(qkvw,  wqkv,  (long long)NLAYER*2304*768);
  cvt(projw, wproj, (long long)NLAYER*768*768);
  cvt(fc1w,  wfc1,  (long long)NLAYER*3072*768);
  cvt(fc2w,  wfc2,  (long long)NLAYER*768*3072);
  cvt(conv_w, wconv, (long long)768*768);
  biaseff_k<<<(NLAYER*2304 + 255)/256, 256, 0, stream>>>(qkvb, bmask, beff, NLAYER*2304);
  ropetab_k<<<2, 256, 0, stream>>>(periods, tab);
  hipMemsetAsync(Q, 0, (size_t)QSZ*2*3, stream);   // Q/K/V pad rows must be zero

  patch_k<<<(MCONV*DIM + 255)/256, 256, 0, stream>>>(pixel, Ap);
  initx_k<<<(BATCH*5*DIM + 255)/256, 256, 0, stream>>>(x, cls, stor);
  gemm128<EPI_CONV,64><<<dim3(DIM/64, MCONV/128), 256, 0, stream>>>(
      Ap, DIM, wconv, DIM, DIM, conv_b, nullptr, x, nullptr);

  for (int l = 0; l < NLAYER; ++l){
    ln_k<0><<<MTOK, 256, 0, stream>>>(x, ln1s + l*DIM, ln1b + l*DIM, h, nullptr);
    gemm128<EPI_QKV,128><<<dim3(2304/128, MPAD2/128), 256, 0, stream>>>(
        h, DIM, wqkv + (long long)l*2304*768, DIM, DIM,
        beff + l*2304, nullptr, nullptr, Q);
    rope_k<<<(BHEADS*576*32 + 255)/256, 256, 0, stream>>>(Q, Kb, tab);
    gemm_k<EPI_S><<<dim3(NPAD/64, NPAD/64, BHEADS), 256, 0, stream>>>(
        Q, (long long)NPAD*HDIM, HDIM, Kb, (long long)NPAD*HDIM, HDIM,
        NPAD, NPAD, HDIM, S, (long long)NPAD*NPAD);
    softmax_k<<<dim3(NTOK, BHEADS), 256, 0, stream>>>(S);
    vt_k<<<(BHEADS*NPAD*HDIM + 255)/256, 256, 0, stream>>>(Vb, VT);
    gemm_k<EPI_PV><<<dim3(1, NPAD/64, BHEADS), 256, 0, stream>>>(
        S, (long long)NPAD*NPAD, NPAD, VT, (long long)HDIM*NPAD, NPAD,
        NPAD, HDIM, NPAD, obuf, 0);
    gemm128<EPI_PROJ,64><<<dim3(DIM/64, MPAD2/128), 256, 0, stream>>>(
        obuf, DIM, wproj + (long long)l*768*768, DIM, DIM,
        projb + l*DIM, ls1 + l*DIM, x, nullptr);
    ln_k<0><<<MTOK, 256, 0, stream>>>(x, ln2s + l*DIM, ln2b + l*DIM, h, nullptr);
    gemm128<EPI_GELU,128><<<dim3(DFF/128, MPAD2/128), 256, 0, stream>>>(
        h, DIM, wfc1 + (long long)l*3072*768, DIM, DIM,
        fc1b + l*DFF, nullptr, nullptr, mlp);
    gemm128<EPI_FC2,64><<<dim3(DIM/64, MPAD2/128), 256, 0, stream>>>(
        mlp, DFF, wfc2 + (long long)l*768*3072, DFF, DFF,
        fc2b + l*DIM, ls2 + l*DIM, x, nullptr);
  }
  ln_k<1><<<MTOK, 256, 0, stream>>>(x, lnfs, lnfb, nullptr, (float*)d_out);
}

// Round 5
// 3914.694 us; speedup vs baseline: 1.1869x; 1.0412x over previous
//
#include <hip/hip_runtime.h>
#include <math.h>

typedef unsigned short u16;
typedef __attribute__((ext_vector_type(8))) short bf8;     // 8 x bf16 (raw bits)
typedef __attribute__((ext_vector_type(4))) float f4;

#define DEV static __device__ __forceinline__

DEV u16 f2b(float f){
  unsigned u = __builtin_bit_cast(unsigned, f);
  u += 0x7fffu + ((u >> 16) & 1u);          // round-to-nearest-even
  return (u16)(u >> 16);
}
DEV float b2f(u16 h){
  unsigned u = ((unsigned)h) << 16;
  return __builtin_bit_cast(float, u);
}

#define BATCH  8
#define NTOK   581
#define NPAD   640
#define DIM    768
#define DFF    3072
#define NHEAD  12
#define HDIM   64
#define NLAYER 12
#define MTOK   (BATCH*NTOK)     /* 4648 */
#define MPAD2  4736             /* 37*128 */
#define MCONV  (BATCH*576)      /* 4608 = 36*128 */
#define ATTN_SCALE 0.125f
#define BHEADS (BATCH*NHEAD)    /* 96 */
#define QSZ    ((long long)BHEADS*NPAD*HDIM)

enum { EPI_CONV=0, EPI_QKV, EPI_S, EPI_PV, EPI_PROJ, EPI_GELU, EPI_FC2 };

#define GLD16(g, l) __builtin_amdgcn_global_load_lds( \
    (const __attribute__((address_space(1))) unsigned*)(g), \
    (__attribute__((address_space(3))) unsigned*)(l), 16, 0, 0)

// ------- 128x128 tile GEMM, BK=32, triple-buffered counted-vmcnt pipeline -------
// C = A(MxK,row) * B(NxK,row)^T. M = gridDim.y*128, N = gridDim.x*128, K%32==0.
// LDS layout per tile: [128 rows][32 cols] bf16, XOR-swizzled: u16 index =
// row*32 + (col ^ (((row>>3)&1)<<4)).  Staged via global_load_lds with the
// inverse (same) permutation applied to the per-lane GLOBAL source address.
template<int EPI>
__global__ __launch_bounds__(256) void gemm3b(
    const u16* __restrict__ A, int lda,
    const u16* __restrict__ B, int ldb, int K,
    const float* __restrict__ bias,
    const float* __restrict__ aux,
    float* __restrict__ Cf,
    u16* __restrict__ Cb)
{
  const int bm = blockIdx.y * 128, bn = blockIdx.x * 128;
  __shared__ __attribute__((aligned(16))) u16 As[3][128*32];
  __shared__ __attribute__((aligned(16))) u16 Bs[3][128*32];
  const int tid  = threadIdx.x;
  const int lane = tid & 63, wid = tid >> 6;
  const int wr = wid >> 1, wc = wid & 1;            // 2x2 waves, each 64x64 of C
  // ---- staging addresses: 16 wave-load units of 1024B (A: 0..7, B: 8..15)
  // physical LDS byte for lane l in unit q: q*1024 + l*16
  // logical byte = physical ^ ((l>=32)<<5)  ->  row = q*16 + (l>>2),
  // col = (l&3)*8 ^ ((l>=32)?16:0)
  const int srow = lane >> 2;
  const int scol = ((lane & 3) * 8) ^ ((lane >= 32) ? 16 : 0);
  const u16* gb[4];
  int lof[4]; bool isA[4];
  #pragma unroll
  for (int j = 0; j < 4; ++j){
    int q = wid * 4 + j;
    if (q < 8){
      gb[j]  = A + (long long)(bm + q*16 + srow) * lda + scol;
      lof[j] = q * 512; isA[j] = true;
    } else {
      int qb = q - 8;
      gb[j]  = B + (long long)(bn + qb*16 + srow) * ldb + scol;
      lof[j] = qb * 512; isA[j] = false;
    }
  }
  auto stage = [&](int kt, int buf){
    #pragma unroll
    for (int j = 0; j < 4; ++j){
      u16* dst = (isA[j] ? &As[buf][0] : &Bs[buf][0]) + lof[j];
      GLD16(gb[j] + kt * 32, dst);
    }
  };
  // ---- fragment read indices (swizzled)
  const int frow = lane & 15;
  const int fk_sw = ((lane >> 4) * 8) ^ (((frow >> 3) & 1) << 4);
  const int ar0 = (wr*64 + frow) * 32 + fk_sw;
  const int br0 = (wc*64 + frow) * 32 + fk_sw;

  f4 acc[4][4] = {};
  const int NT = K >> 5;
  stage(0, 0); stage(1, 1);
  __builtin_amdgcn_sched_barrier(0);
  asm volatile("s_waitcnt vmcnt(4)" ::: "memory");
  __builtin_amdgcn_s_barrier();
  __builtin_amdgcn_sched_barrier(0);
  int cur = 0;
  for (int t = 0; t < NT; ++t){
    int sb = (cur >= 1) ? cur - 1 : 2;              // (t+2)%3
    if (t + 2 < NT) stage(t + 2, sb);
    const u16* Ab = &As[cur][0];
    const u16* Bb = &Bs[cur][0];
    bf8 a[4], b[4];
    #pragma unroll
    for (int m = 0; m < 4; ++m) a[m] = *(const bf8*)&Ab[ar0 + m*512];
    #pragma unroll
    for (int n = 0; n < 4; ++n) b[n] = *(const bf8*)&Bb[br0 + n*512];
    __builtin_amdgcn_s_setprio(1);
    #pragma unroll
    for (int m = 0; m < 4; ++m)
    #pragma unroll
    for (int n = 0; n < 4; ++n)
      acc[m][n] = __builtin_amdgcn_mfma_f32_16x16x32_bf16(a[m], b[n], acc[m][n], 0, 0, 0);
    __builtin_amdgcn_s_setprio(0);
    __builtin_amdgcn_sched_barrier(0);
    if (t + 2 < NT) asm volatile("s_waitcnt vmcnt(4)" ::: "memory");
    else            asm volatile("s_waitcnt vmcnt(0)" ::: "memory");
    __builtin_amdgcn_s_barrier();
    __builtin_amdgcn_sched_barrier(0);
    cur = (cur >= 2) ? 0 : cur + 1;
  }
  #pragma unroll
  for (int mi = 0; mi < 4; ++mi)
  #pragma unroll
  for (int ni = 0; ni < 4; ++ni){
    f4 v = acc[mi][ni];
    int col = bn + wc*64 + ni*16 + frow;
    int r0  = bm + wr*64 + mi*16 + (lane >> 4) * 4;
    #pragma unroll
    for (int j = 0; j < 4; ++j){
      int m = r0 + j;
      float val = v[j];
      if constexpr (EPI == EPI_CONV){
        int b = m / 576, p = m % 576;
        Cf[((long long)b*NTOK + 5 + p)*DIM + col] = val + bias[col];
      } else if constexpr (EPI == EPI_QKV){
        if (m < MTOK){
          int b = m / NTOK, t = m % NTOK;
          int which = col / DIM, rem = col % DIM;
          int h = rem / HDIM, hd = rem % HDIM;
          float x = val + bias[col];
          if (which == 0) x *= ATTN_SCALE;
          Cb[(long long)which*QSZ + (((long long)(b*NHEAD + h))*NPAD + t)*HDIM + hd] = f2b(x);
        }
      } else if constexpr (EPI == EPI_PROJ || EPI == EPI_FC2){
        if (m < MTOK)
          Cf[(long long)m*DIM + col] += aux[col] * (val + bias[col]);
      } else if constexpr (EPI == EPI_GELU){
        float x = val + bias[col];
        float g = 0.5f * x * (1.0f + erff(x * 0.70710678118f));
        Cb[(long long)m*DFF + col] = f2b(g);
      }
    }
  }
}

// ---------------- 64x64 tile GEMM (attention S / PV) ----------------
template<int EPI>
__global__ __launch_bounds__(256) void gemm_k(
    const u16* __restrict__ A, long long sAz, int lda,
    const u16* __restrict__ B, long long sBz, int ldb,
    int M, int N, int K,
    u16* __restrict__ Cb, long long sCz)
{
  const int z = blockIdx.z;
  const u16* Ab = A + (long long)z * sAz;
  const u16* Bb = B + (long long)z * sBz;
  const int bm = blockIdx.y * 64, bn = blockIdx.x * 64;
  __shared__ __attribute__((aligned(16))) u16 As[64][40];
  __shared__ __attribute__((aligned(16))) u16 Bs[64][40];
  const int tid  = threadIdx.x;
  const int lane = tid & 63, wid = tid >> 6;
  const int wr = wid >> 1, wc = wid & 1;          // 2x2 waves, each 32x32
  const int lr = tid >> 2, lc = (tid & 3) * 8;    // staging: 1 x 16B per thread
  const int frow = lane & 15, fk = (lane >> 4) * 8;
  f4 acc[2][2] = {};
  for (int k0 = 0; k0 < K; k0 += 32){
    *(bf8*)&As[lr][lc] = *(const bf8*)&Ab[(long long)(bm + lr) * lda + k0 + lc];
    *(bf8*)&Bs[lr][lc] = *(const bf8*)&Bb[(long long)(bn + lr) * ldb + k0 + lc];
    __syncthreads();
    bf8 a0 = *(const bf8*)&As[wr*32 +      frow][fk];
    bf8 a1 = *(const bf8*)&As[wr*32 + 16 + frow][fk];
    bf8 b0 = *(const bf8*)&Bs[wc*32 +      frow][fk];
    bf8 b1 = *(const bf8*)&Bs[wc*32 + 16 + frow][fk];
    acc[0][0] = __builtin_amdgcn_mfma_f32_16x16x32_bf16(a0, b0, acc[0][0], 0, 0, 0);
    acc[0][1] = __builtin_amdgcn_mfma_f32_16x16x32_bf16(a0, b1, acc[0][1], 0, 0, 0);
    acc[1][0] = __builtin_amdgcn_mfma_f32_16x16x32_bf16(a1, b0, acc[1][0], 0, 0, 0);
    acc[1][1] = __builtin_amdgcn_mfma_f32_16x16x32_bf16(a1, b1, acc[1][1], 0, 0, 0);
    __syncthreads();
  }
  #pragma unroll
  for (int mi = 0; mi < 2; ++mi)
  #pragma unroll
  for (int ni = 0; ni < 2; ++ni){
    f4 v = acc[mi][ni];
    int col = bn + wc*32 + ni*16 + frow;
    int r0  = bm + wr*32 + mi*16 + (lane >> 4) * 4;
    #pragma unroll
    for (int j = 0; j < 4; ++j){
      int m = r0 + j;
      float val = v[j];
      if constexpr (EPI == EPI_S){
        Cb[(long long)z*sCz + (long long)m*NPAD + col] = f2b(val);
      } else if constexpr (EPI == EPI_PV){
        if (m < NTOK)
          Cb[(((long long)(z / NHEAD))*NTOK + m)*DIM + (z % NHEAD)*HDIM + col] = f2b(val);
      }
    }
  }
}

// LayerNorm over D=768 per row; writes bf16 (F32OUT=0) or f32 (F32OUT=1).
template<int F32OUT>
__global__ __launch_bounds__(256) void ln_k(const float* __restrict__ x,
    const float* __restrict__ s, const float* __restrict__ b,
    u16* __restrict__ ob, float* __restrict__ of)
{
  const long long row = blockIdx.x;
  const float* xr = x + row * DIM;
  const int t = threadIdx.x;
  float v0 = xr[t], v1 = xr[t + 256], v2 = xr[t + 512];
  float sum = v0 + v1 + v2;
  #pragma unroll
  for (int o = 32; o; o >>= 1) sum += __shfl_down(sum, o);
  __shared__ float r1[4], r2[4];
  const int lane = t & 63, w = t >> 6;
  if (lane == 0) r1[w] = sum;
  __syncthreads();
  float mu = (r1[0] + r1[1] + r1[2] + r1[3]) * (1.0f / DIM);
  float d0 = v0 - mu, d1 = v1 - mu, d2 = v2 - mu;
  float vs = d0*d0 + d1*d1 + d2*d2;
  #pragma unroll
  for (int o = 32; o; o >>= 1) vs += __shfl_down(vs, o);
  if (lane == 0) r2[w] = vs;
  __syncthreads();
  float inv = 1.0f / sqrtf((r2[0] + r2[1] + r2[2] + r2[3]) * (1.0f / DIM) + 1e-6f);
  if constexpr (F32OUT){
    float* orow = of + row * DIM;
    orow[t]       = d0 * inv * s[t]       + b[t];
    orow[t + 256] = d1 * inv * s[t + 256] + b[t + 256];
    orow[t + 512] = d2 * inv * s[t + 512] + b[t + 512];
  } else {
    u16* orow = ob + row * DIM;
    orow[t]       = f2b(d0 * inv * s[t]       + b[t]);
    orow[t + 256] = f2b(d1 * inv * s[t + 256] + b[t + 256]);
    orow[t + 512] = f2b(d2 * inv * s[t + 512] + b[t + 512]);
  }
}

// Row softmax over cols [0,581); zeroes pad cols [581,640). In-place on bf16 S.
__global__ __launch_bounds__(256) void softmax_k(u16* __restrict__ S)
{
  const long long base = ((long long)blockIdx.y * NPAD + blockIdx.x) * NPAD;
  const int t = threadIdx.x;
  float v0 = b2f(S[base + t]);
  float v1 = b2f(S[base + t + 256]);
  const bool has2 = (t + 512) < NTOK;
  float v2 = has2 ? b2f(S[base + t + 512]) : -1e30f;
  float mx = fmaxf(fmaxf(v0, v1), v2);
  #pragma unroll
  for (int o = 32; o; o >>= 1) mx = fmaxf(mx, __shfl_down(mx, o));
  __shared__ float r1[4], r2[4];
  const int lane = t & 63, w = t >> 6;
  if (lane == 0) r1[w] = mx;
  __syncthreads();
  mx = fmaxf(fmaxf(r1[0], r1[1]), fmaxf(r1[2], r1[3]));
  float e0 = expf(v0 - mx), e1 = expf(v1 - mx), e2 = has2 ? expf(v2 - mx) : 0.0f;
  float sm = e0 + e1 + e2;
  #pragma unroll
  for (int o = 32; o; o >>= 1) sm += __shfl_down(sm, o);
  if (lane == 0) r2[w] = sm;
  __syncthreads();
  float inv = 1.0f / (r2[0] + r2[1] + r2[2] + r2[3]);
  S[base + t]       = f2b(e0 * inv);
  S[base + t + 256] = f2b(e1 * inv);
  if (t + 512 < NPAD) S[base + t + 512] = f2b(has2 ? e2 * inv : 0.0f);
}

__global__ void ropetab_k(const float* __restrict__ periods, float* __restrict__ tab)
{
  int idx = blockIdx.x * blockDim.x + threadIdx.x;
  if (idx >= 24 * 16) return;
  int c = idx >> 4, f = idx & 15;
  float fr = 6.283185307179586f / periods[f];
  float a = (float)c * fr;
  tab[idx]       = cosf(a);
  tab[384 + idx] = sinf(a);
}

__global__ __launch_bounds__(256) void rope_k(u16* __restrict__ Q, u16* __restrict__ K,
                                              const float* __restrict__ tab)
{
  int idx = blockIdx.x * blockDim.x + threadIdx.x;
  if (idx >= BHEADS * 576 * 32) return;
  int f  = idx & 31;
  int p  = (idx >> 5) % 576;
  int bh = idx / (576 * 32);
  int px = p % 24, py = p / 24;
  float c, s; int d0;
  if (f < 16){ c = tab[px*16 + f];        s = tab[384 + px*16 + f];        d0 = 2*f; }
  else       { int ff = f - 16;
               c = tab[py*16 + ff];       s = tab[384 + py*16 + ff];       d0 = 32 + 2*ff; }
  long long off = (((long long)bh) * NPAD + 5 + p) * HDIM + d0;
  float qe = b2f(Q[off]), qo = b2f(Q[off + 1]);
  Q[off]     = f2b(qe * c - qo * s);
  Q[off + 1] = f2b(qe * s + qo * c);
  float ke = b2f(K[off]), ko = b2f(K[off + 1]);
  K[off]     = f2b(ke * c - ko * s);
  K[off + 1] = f2b(ke * s + ko * c);
}

__global__ void initx_k(float* __restrict__ x, const float* __restrict__ cls,
                        const float* __restrict__ stor)
{
  int idx = blockIdx.x * blockDim.x + threadIdx.x;
  if (idx >= BATCH * 5 * DIM) return;
  int d = idx % DIM; int t = (idx / DIM) % 5; int b = idx / (5 * DIM);
  x[((long long)b * NTOK + t) * DIM + d] = (t == 0) ? cls[d] : stor[(t - 1) * DIM + d];
}

__global__ void patch_k(const float* __restrict__ px, u16* __restrict__ Ap)
{
  int idx = blockIdx.x * blockDim.x + threadIdx.x;
  if (idx >= MCONV * DIM) return;
  int k = idx % DIM, m = idx / DIM;
  int b = m / 576, r = m % 576, hp = r / 24, wp = r % 24;
  int c = k / 256, rem = k % 256, p = rem / 16, q = rem % 16;
  float v = px[((((long long)b * 3 + c) * 384) + hp * 16 + p) * 384 + wp * 16 + q];
  Ap[idx] = f2b(v);
}

__global__ void vt_k(const u16* __restrict__ V, u16* __restrict__ VT)
{
  int idx = blockIdx.x * blockDim.x + threadIdx.x;
  if (idx >= BHEADS * NPAD * HDIM) return;
  int hd = idx % HDIM; int t = (idx / HDIM) % NPAD; int bh = idx / (NPAD * HDIM);
  VT[(((long long)bh) * HDIM + hd) * NPAD + t] = V[idx];
}

__global__ void cvt_k(const float* __restrict__ src, u16* __restrict__ dst, long long n)
{
  long long i = (long long)blockIdx.x * blockDim.x + threadIdx.x;
  long long stride = (long long)gridDim.x * blockDim.x;
  for (; i < n; i += stride) dst[i] = f2b(src[i]);
}

__global__ void biaseff_k(const float* __restrict__ qb, const float* __restrict__ bm,
                          float* __restrict__ out, int n)
{
  int i = blockIdx.x * blockDim.x + threadIdx.x;
  if (i < n) out[i] = qb[i] * bm[i];
}

extern "C" void kernel_launch(void* const* d_in, const int* in_sizes, int n_in,
                              void* d_out, int out_size, void* d_ws, size_t ws_size,
                              hipStream_t stream)
{
  const float* pixel   = (const float*)d_in[0];
  const float* conv_w  = (const float*)d_in[1];
  const float* conv_b  = (const float*)d_in[2];
  const float* cls     = (const float*)d_in[3];
  const float* stor    = (const float*)d_in[4];
  const float* periods = (const float*)d_in[5];
  const float* ln1s    = (const float*)d_in[6];
  const float* ln1b    = (const float*)d_in[7];
  const float* qkvw    = (const float*)d_in[8];
  const float* qkvb    = (const float*)d_in[9];
  const float* bmask   = (const float*)d_in[10];
  const float* projw   = (const float*)d_in[11];
  const float* projb   = (const float*)d_in[12];
  const float* ls1     = (const float*)d_in[13];
  const float* ln2s    = (const float*)d_in[14];
  const float* ln2b    = (const float*)d_in[15];
  const float* fc1w    = (const float*)d_in[16];
  const float* fc1b    = (const float*)d_in[17];
  const float* fc2w    = (const float*)d_in[18];
  const float* fc2b    = (const float*)d_in[19];
  const float* ls2     = (const float*)d_in[20];
  const float* lnfs    = (const float*)d_in[21];
  const float* lnfb    = (const float*)d_in[22];

  char* wsp = (char*)d_ws;
  auto alloc = [&](long long bytes) -> char* {
    char* p = wsp; wsp += (bytes + 255) & ~255LL; return p;
  };
  u16*   wqkv  = (u16*)  alloc((long long)NLAYER*2304*768*2);
  u16*   wproj = (u16*)  alloc((long long)NLAYER*768*768*2);
  u16*   wfc1  = (u16*)  alloc((long long)NLAYER*3072*768*2);
  u16*   wfc2  = (u16*)  alloc((long long)NLAYER*768*3072*2);
  u16*   wconv = (u16*)  alloc((long long)768*768*2);
  float* beff  = (float*)alloc((long long)NLAYER*2304*4);
  float* x     = (float*)alloc((long long)MPAD2*DIM*4);
  u16*   h     = (u16*)  alloc((long long)MPAD2*DIM*2);
  u16*   obuf  = (u16*)  alloc((long long)MPAD2*DIM*2);
  u16*   mlp   = (u16*)  alloc((long long)MPAD2*DFF*2);
  u16*   Ap    = (u16*)  alloc((long long)MCONV*DIM*2);
  u16*   Q     = (u16*)  alloc(QSZ*2*3);
  u16*   Kb    = Q + QSZ;
  u16*   Vb    = Q + 2*QSZ;
  u16*   VT    = (u16*)  alloc(QSZ*2);
  u16*   S     = (u16*)  alloc((long long)BHEADS*NPAD*NPAD*2);
  float* tab   = (float*)alloc((long long)2*24*16*4);
  if ((size_t)(wsp - (char*)d_ws) > ws_size) return;  // workspace too small

  auto cvt = [&](const float* src, u16* dst, long long n){
    long long nb = (n + 255) / 256; if (nb > 4096) nb = 4096;
    cvt_k<<<(int)nb, 256, 0, stream>>>(src, dst, n);
  };
  cvt(qkvw,  wqkv,  (long long)NLAYER*2304*768);
  cvt(projw, wproj, (long long)NLAYER*768*768);
  cvt(fc1w,  wfc1,  (long long)NLAYER*3072*768);
  cvt(fc2w,  wfc2,  (long long)NLAYER*768*3072);
  cvt(conv_w, wconv, (long long)768*768);
  biaseff_k<<<(NLAYER*2304 + 255)/256, 256, 0, stream>>>(qkvb, bmask, beff, NLAYER*2304);
  ropetab_k<<<2, 256, 0, stream>>>(periods, tab);
  hipMemsetAsync(Q, 0, (size_t)QSZ*2*3, stream);   // Q/K/V pad rows must be zero

  patch_k<<<(MCONV*DIM + 255)/256, 256, 0, stream>>>(pixel, Ap);
  initx_k<<<(BATCH*5*DIM + 255)/256, 256, 0, stream>>>(x, cls, stor);
  gemm3b<EPI_CONV><<<dim3(DIM/128, MCONV/128), 256, 0, stream>>>(
      Ap, DIM, wconv, DIM, DIM, conv_b, nullptr, x, nullptr);

  for (int l = 0; l < NLAYER; ++l){
    ln_k<0><<<MTOK, 256, 0, stream>>>(x, ln1s + l*DIM, ln1b + l*DIM, h, nullptr);
    gemm3b<EPI_QKV><<<dim3(2304/128, MPAD2/128), 256, 0, stream>>>(
        h, DIM, wqkv + (long long)l*2304*768, DIM, DIM,
        beff + l*2304, nullptr, nullptr, Q);
    rope_k<<<(BHEADS*576*32 + 255)/256, 256, 0, stream>>>(Q, Kb, tab);
    gemm_k<EPI_S><<<dim3(NPAD/64, NPAD/64, BHEADS), 256, 0, stream>>>(
        Q, (long long)NPAD*HDIM, HDIM, Kb, (long long)NPAD*HDIM, HDIM,
        NPAD, NPAD, HDIM, S, (long long)NPAD*NPAD);
    softmax_k<<<dim3(NTOK, BHEADS), 256, 0, stream>>>(S);
    vt_k<<<(BHEADS*NPAD*HDIM + 255)/256, 256, 0, stream>>>(Vb, VT);
    gemm_k<EPI_PV><<<dim3(1, NPAD/64, BHEADS), 256, 0, stream>>>(
        S, (long long)NPAD*NPAD, NPAD, VT, (long long)HDIM*NPAD, NPAD,
        NPAD, HDIM, NPAD, obuf, 0);
    gemm3b<EPI_PROJ><<<dim3(DIM/128, MPAD2/128), 256, 0, stream>>>(
        obuf, DIM, wproj + (long long)l*768*768, DIM, DIM,
        projb + l*DIM, ls1 + l*DIM, x, nullptr);
    ln_k<0><<<MTOK, 256, 0, stream>>>(x, ln2s + l*DIM, ln2b + l*DIM, h, nullptr);
    gemm3b<EPI_GELU><<<dim3(DFF/128, MPAD2/128), 256, 0, stream>>>(
        h, DIM, wfc1 + (long long)l*3072*768, DIM, DIM,
        fc1b + l*DFF, nullptr, nullptr, mlp);
    gemm3b<EPI_FC2><<<dim3(DIM/128, MPAD2/128), 256, 0, stream>>>(
        mlp, DFF, wfc2 + (long long)l*768*3072, DFF, DFF,
        fc2b + l*DIM, ls2 + l*DIM, x, nullptr);
  }
  ln_k<1><<<MTOK, 256, 0, stream>>>(x, lnfs, lnfb, nullptr, (float*)d_out);
}